// Round 10
// baseline (102.101 us; speedup 1.0000x reference)
//
#include <hip/hip_runtime.h>
#include <hip/hip_bf16.h>

// Problem constants
#define NB   8
#define NC   256
#define HW   56
#define NPX  3136          // 56*56
#define RED  64
#define NG   16
#define GC   16
#define KS   7
#define KK   49
#define PADK 3
#define XPH  62            // padded rows: 3 + 56 + 3
#define XPW  64            // padded row stride
#define XPSLICE (XPH * XPW)   // 3968 floats per channel slice
#define TPX  224           // K2 px tile = 4 full pixel rows
#define NTILE 14           // 3136 / 224
#define XT_RS 68           // xtap row stride (f32) - breaks 4-row bank alias
#define XT_CS (10 * XT_RS) // xtap ch stride = 680
#define WSTR 224           // wls px stride (bf16 elems); row = 448 B (8-mult)

typedef float f32x4 __attribute__((ext_vector_type(4)));
typedef float f32x2 __attribute__((ext_vector_type(2)));
typedef short short8 __attribute__((ext_vector_type(8)));

// ---------------------------------------------------------------------------
// K0a: zero only the BORDER of xpad (832 elems/slice); interior written by K1.
// ---------------------------------------------------------------------------
__global__ __launch_bounds__(256) void border_kernel(float* __restrict__ xpad) {
    int bc = blockIdx.x;                       // 0 .. NB*NC-1
    float* xd = xpad + (size_t)bc * XPSLICE;
#pragma unroll
    for (int e = threadIdx.x; e < 832; e += 256) {
        int row, col;
        if (e < 192)      { row = e >> 6;              col = e & 63; }
        else if (e < 384) { int f = e - 192; row = 59 + (f >> 6); col = f & 63; }
        else              { int f = e - 384; row = 3 + (f >> 3);
                            int c8 = f & 7;  col = (c8 < 3) ? c8 : 56 + c8; }
        xd[row * XPW + col] = 0.0f;
    }
}

// ---------------------------------------------------------------------------
// K0b: w2 [16g*49][64] fp32 -> w2bf [g][64m][64k] bf16 (rows 49..63 zero).
// ---------------------------------------------------------------------------
__global__ __launch_bounds__(256) void prep_w2_kernel(
    const float* __restrict__ w2, __hip_bfloat16* __restrict__ w2bf) {
    int g = blockIdx.x;                        // 0..15
#pragma unroll 4
    for (int e = threadIdx.x; e < 64 * 64; e += 256) {
        int m = e >> 6, k = e & 63;
        float v = (m < KK) ? w2[((size_t)g * KK + m) * RED + k] : 0.0f;
        w2bf[(size_t)g * 4096 + e] = __float2bfloat16(v);
    }
}

// ---------------------------------------------------------------------------
// K1: t = relu(bn1(conv1x1(x, w1))) -> bf16, AND scatter x into xpad interior.
// Grid 784 1D (XCD-swizzled, 8x98) x 256 thr (4 waves).
// ---------------------------------------------------------------------------
__global__ __launch_bounds__(256) void conv1_kernel(
    const float* __restrict__ x, const float* __restrict__ w1,
    const float* __restrict__ g1, const float* __restrict__ be1,
    const float* __restrict__ mu1, const float* __restrict__ var1,
    __hip_bfloat16* __restrict__ t, float* __restrict__ xpad) {
    int lane = threadIdx.x & 63;
    int wv   = __builtin_amdgcn_readfirstlane(threadIdx.x >> 6);  // 0..3 SGPR
    // XCD swizzle: 784 = 8 * 98; logical = b*98 + half*49 + tile
    int wgid = blockIdx.x;
    int swz  = (wgid & 7) * 98 + (wgid >> 3);
    int b    = swz / 98;
    int rem  = swz % 98;
    int half = rem / 49;
    int tile = rem % 49;
    int rq = half * 4 + wv;                    // 0..7 -> outputs rq*8..rq*8+7
    int px = tile * 64 + lane;
    int h = px / HW, w = px % HW;

    const float* xb = x + (size_t)b * NC * NPX + px;
    float* xpw = xpad + (size_t)b * NC * XPSLICE + (h + PADK) * XPW + (w + PADK);

    float acc[8];
#pragma unroll
    for (int j = 0; j < 8; ++j) acc[j] = 0.0f;

#pragma unroll 2
    for (int c0 = 0; c0 < NC; c0 += 16) {
        float xv[16];
#pragma unroll
        for (int i = 0; i < 16; ++i) xv[i] = xb[(size_t)(c0 + i) * NPX];
        if (half == 0 && wv == 0) {            // block+wave-uniform branch
#pragma unroll
            for (int i = 0; i < 16; ++i)
                xpw[(size_t)(c0 + i) * XPSLICE] = xv[i];
        }
#pragma unroll
        for (int j = 0; j < 8; ++j) {
            const float* wrow = w1 + (rq * 8 + j) * NC + c0;   // s_load
#pragma unroll
            for (int i = 0; i < 16; ++i)
                acc[j] = fmaf(xv[i], wrow[i], acc[j]);
        }
    }

    __hip_bfloat16* tb = t + (size_t)b * RED * NPX + px;
#pragma unroll
    for (int j = 0; j < 8; ++j) {
        int o = rq * 8 + j;
        float inv = g1[o] * rsqrtf(var1[o] + 1e-5f);
        float v = acc[j] * inv + (be1[o] - mu1[o] * inv);
        tb[(size_t)o * NPX] = __float2bfloat16(fmaxf(v, 0.0f));
    }
}

// ---------------------------------------------------------------------------
// K2: fused conv2(MFMA) -> involution -> bn2 -> relu.
// Tile = 224 px (4 full pixel rows) x 16 ch (one group). Grid 1792
// (XCD-swizzled 8x224: each XCD owns one batch), 256 thr (4 waves).
// LDS: xtap f32 [16ch][10rows][68] (43.5 KB) + wls bf16 [49][224] (21.9 KB)
//      = 65,472 B (just under 64 KB cap) -> 2 blocks/CU.
// Step 1 (T14): issue 10 f32x4 xtap loads (global->reg), written after A.
// Step 2 (phase A): per wave, N-tiles nt = wv+4*it (14 total): MFMA
//   wgt = w2g[49x64] . t[64 x 16px]; C+bias converted to bf16 -> wls[k][px].
// Step 3: reg->LDS xtap writes, one barrier.
// Step 4 (phase B): lane = px-quad (56 of 64 active), wave = 4 channels.
//   Per (i,j): ONE b64 wls read (4 bf16) serves 16 FMA (4ch x 4px) -- the
//   wgt-broadcast waste of r9 is gone. Taps: 2 b128 + 1 b64 per (ch,row).
//   bn2+relu, f32x4 coalesced store.
// ---------------------------------------------------------------------------
__global__ __launch_bounds__(256, 2) void involution_kernel(
    const float* __restrict__ xpad, const __hip_bfloat16* __restrict__ t,
    const __hip_bfloat16* __restrict__ w2bf, const float* __restrict__ b2,
    const float* __restrict__ g2, const float* __restrict__ be2,
    const float* __restrict__ mu2, const float* __restrict__ var2,
    float* __restrict__ out) {
    __shared__ __align__(16) float  xtap[GC * XT_CS];    // 43,520 B
    __shared__ __align__(16) unsigned short wls[KK * WSTR]; // 21,952 B

    int tid  = threadIdx.x;
    int lane = tid & 63;
    int wv   = __builtin_amdgcn_readfirstlane(tid >> 6);   // 0..3 SGPR
    // XCD swizzle: 1792 = 8 * 224; logical = b*224 + g*14 + tile
    int wgid = blockIdx.x;
    int swz  = (wgid & 7) * 224 + (wgid >> 3);
    int tile = swz % NTILE;
    int g    = (swz / NTILE) & 15;
    int b    = swz / 224;
    int px0 = tile * TPX;
    int R0  = tile * 4;                        // first output pixel-row

    // ---- step 1: issue xtap global loads (held in regs across phase A) ----
    const float* xpg = xpad + ((size_t)b * NC + (size_t)g * GC) * XPSLICE;
    f32x4 xr[10];
#pragma unroll
    for (int u = 0; u < 10; ++u) {
        int cid = u * 256 + tid;               // 0..2559 16B-chunks
        int c16 = cid & 15;
        int t4  = cid >> 4;                    // 0..159
        int rr  = t4 % 10;
        int ch  = t4 / 10;
        xr[u] = *(const f32x4*)(xpg + (size_t)ch * XPSLICE + (R0 + rr) * XPW + c16 * 4);
    }

    // ---- step 2: phase A MFMA  wgt[49 x 224px] = w2g[49x64r] . t[64r x px] ----
    {
        int l15 = lane & 15, l4 = lane >> 4;
        const short* wA = (const short*)w2bf + (size_t)g * 4096;
        const float* bg = b2 + (size_t)g * KK;
        const unsigned short* tgb =
            (const unsigned short*)t + (size_t)b * RED * NPX + px0;
#pragma unroll
        for (int it = 0; it < 4; ++it) {
            int nt = wv + it * 4;              // wave-uniform
            if (nt < NTILE) {
                const unsigned short* tg = tgb + nt * 16 + l15;
                short8 bfr0, bfr1;
#pragma unroll
                for (int i2 = 0; i2 < 8; ++i2) {
                    bfr0[i2] = (short)tg[(size_t)(l4 * 8 + i2) * NPX];
                    bfr1[i2] = (short)tg[(size_t)(32 + l4 * 8 + i2) * NPX];
                }
                f32x4 acc0 = {0,0,0,0}, acc1 = {0,0,0,0},
                      acc2 = {0,0,0,0}, acc3 = {0,0,0,0};
#pragma unroll
                for (int mt = 0; mt < 4; ++mt) {
                    const short* ap = wA + (mt * 16 + l15) * 64 + l4 * 8;
                    short8 a0 = *(const short8*)(ap);
                    short8 a1 = *(const short8*)(ap + 32);
                    f32x4 a = (mt == 0) ? acc0 : (mt == 1) ? acc1
                            : (mt == 2) ? acc2 : acc3;
                    a = __builtin_amdgcn_mfma_f32_16x16x32_bf16(a0, bfr0, a, 0, 0, 0);
                    a = __builtin_amdgcn_mfma_f32_16x16x32_bf16(a1, bfr1, a, 0, 0, 0);
                    if (mt == 0) acc0 = a; else if (mt == 1) acc1 = a;
                    else if (mt == 2) acc2 = a; else acc3 = a;
                }
                // C write: wls[k][nt*16+l15] bf16, k = mt*16 + l4*4 + r
#pragma unroll
                for (int mt = 0; mt < 4; ++mt) {
                    f32x4 a = (mt == 0) ? acc0 : (mt == 1) ? acc1
                            : (mt == 2) ? acc2 : acc3;
#pragma unroll
                    for (int r = 0; r < 4; ++r) {
                        int k = mt * 16 + l4 * 4 + r;
                        if (k < KK) {
                            __hip_bfloat16 hv = __float2bfloat16(a[r] + bg[k]);
                            wls[k * WSTR + nt * 16 + l15] =
                                *(unsigned short*)&hv;
                        }
                    }
                }
            }
        }
    }

    // ---- step 3: write xtap regs to LDS, single barrier ----
#pragma unroll
    for (int u = 0; u < 10; ++u) {
        int cid = u * 256 + tid;
        int c16 = cid & 15;
        int t4  = cid >> 4;
        int rr  = t4 % 10;
        int ch  = t4 / 10;
        *(f32x4*)&xtap[ch * XT_CS + rr * XT_RS + c16 * 4] = xr[u];
    }
    __syncthreads();

    // ---- step 4: phase B, lane = px-quad, wave = 4 channels ----
    if (lane < 56) {
        int q  = lane;                         // quad 0..55
        int lh = q / 14;                       // local output row 0..3
        int w0 = (q % 14) * 4;                 // col 0..52 (mult of 4)
        int cb = wv * 4;                       // this wave's channel base

        float acc[16];
#pragma unroll
        for (int e = 0; e < 16; ++e) acc[e] = 0.0f;

#pragma unroll
        for (int i = 0; i < KS; ++i) {
            float tr[4][10];
#pragma unroll
            for (int cc = 0; cc < 4; ++cc) {
                const float* xb_ = xtap + (cb + cc) * XT_CS + (lh + i) * XT_RS + w0;
                f32x4 t0 = *(const f32x4*)(xb_);
                f32x4 t1 = *(const f32x4*)(xb_ + 4);
                f32x2 t2 = *(const f32x2*)(xb_ + 8);
                tr[cc][0] = t0.x; tr[cc][1] = t0.y; tr[cc][2] = t0.z; tr[cc][3] = t0.w;
                tr[cc][4] = t1.x; tr[cc][5] = t1.y; tr[cc][6] = t1.z; tr[cc][7] = t1.w;
                tr[cc][8] = t2.x; tr[cc][9] = t2.y;
            }
#pragma unroll
            for (int j = 0; j < KS; ++j) {
                uint2 wp = *(const uint2*)&wls[(i * KS + j) * WSTR + q * 4];
                float wf0 = __uint_as_float(wp.x << 16);
                float wf1 = __uint_as_float(wp.x & 0xffff0000u);
                float wf2 = __uint_as_float(wp.y << 16);
                float wf3 = __uint_as_float(wp.y & 0xffff0000u);
#pragma unroll
                for (int cc = 0; cc < 4; ++cc) {
                    acc[cc * 4 + 0] = fmaf(wf0, tr[cc][j + 0], acc[cc * 4 + 0]);
                    acc[cc * 4 + 1] = fmaf(wf1, tr[cc][j + 1], acc[cc * 4 + 1]);
                    acc[cc * 4 + 2] = fmaf(wf2, tr[cc][j + 2], acc[cc * 4 + 2]);
                    acc[cc * 4 + 3] = fmaf(wf3, tr[cc][j + 3], acc[cc * 4 + 3]);
                }
            }
        }

        // bn2 + relu + store
#pragma unroll
        for (int cc = 0; cc < 4; ++cc) {
            int c_ = g * GC + cb + cc;
            float inv = g2[c_] * rsqrtf(var2[c_] + 1e-5f);
            float off = be2[c_] - mu2[c_] * inv;
            f32x4 o;
#pragma unroll
            for (int p = 0; p < 4; ++p)
                o[p] = fmaxf(acc[cc * 4 + p] * inv + off, 0.0f);
            *(f32x4*)(out + ((size_t)b * NC + c_) * NPX + px0 + q * 4) = o;
        }
    }
}

// ---------------------------------------------------------------------------
extern "C" void kernel_launch(void* const* d_in, const int* in_sizes, int n_in,
                              void* d_out, int out_size, void* d_ws, size_t ws_size,
                              hipStream_t stream) {
    const float* x    = (const float*)d_in[0];
    const float* w1   = (const float*)d_in[1];
    const float* g1   = (const float*)d_in[2];
    const float* be1  = (const float*)d_in[3];
    const float* mu1  = (const float*)d_in[4];
    const float* var1 = (const float*)d_in[5];
    const float* w2   = (const float*)d_in[6];
    const float* b2   = (const float*)d_in[7];
    const float* g2   = (const float*)d_in[8];
    const float* be2  = (const float*)d_in[9];
    const float* mu2  = (const float*)d_in[10];
    const float* var2 = (const float*)d_in[11];
    float* outp = (float*)d_out;

    // ws: xpad f32 (32.5 MB) | t bf16 (3.2 MB) | w2bf bf16 (128 KB)
    float* xpad = (float*)d_ws;
    char* p = (char*)d_ws + (size_t)NB * NC * XPSLICE * sizeof(float);
    __hip_bfloat16* t = (__hip_bfloat16*)p;
    p += (size_t)NB * RED * NPX * sizeof(__hip_bfloat16);
    __hip_bfloat16* w2bf = (__hip_bfloat16*)p;

    prep_w2_kernel<<<NG, 256, 0, stream>>>(w2, w2bf);
    border_kernel<<<NB * NC, 256, 0, stream>>>(xpad);
    conv1_kernel<<<784, 256, 0, stream>>>(
        x, w1, g1, be1, mu1, var1, t, xpad);
    involution_kernel<<<1792, 256, 0, stream>>>(
        xpad, t, w2bf, b2, g2, be2, mu2, var2, outp);
}

// Round 11
// 88.312 us; speedup vs baseline: 1.1561x; 1.1561x over previous
//
#include <hip/hip_runtime.h>
#include <hip/hip_bf16.h>

// Problem constants
#define NB   8
#define NC   256
#define HW   56
#define NPX  3136          // 56*56
#define RED  64
#define NG   16
#define GC   16
#define KS   7
#define KK   49
#define PADK 3
#define XPH  62            // padded rows: 3 + 56 + 3
#define XPW  64            // padded row stride (elements)
#define XPSLICE (XPH * XPW)   // 3968 bf16 per channel slice
#define XT_RS 72           // xtap row stride (bf16): 144 B, 16B-multiple
#define XT_CS 580          // xtap ch stride (bf16): 8*72+4 -> 16 distinct bank classes
#define WSTR  68           // wls px stride (bf16): rows 136 B, 8B-multiple

typedef float f32x4 __attribute__((ext_vector_type(4)));
typedef short short8 __attribute__((ext_vector_type(8)));
typedef unsigned short u16x4 __attribute__((ext_vector_type(4)));
typedef unsigned short u16x8 __attribute__((ext_vector_type(8)));

__device__ __forceinline__ float bf2f(unsigned short u) {
    return __uint_as_float(((unsigned int)u) << 16);
}

// ---------------------------------------------------------------------------
// K0a: zero only the BORDER of xpad (bf16); interior written by K1.
// ---------------------------------------------------------------------------
__global__ __launch_bounds__(256) void border_kernel(
    unsigned short* __restrict__ xpad) {
    int bc = blockIdx.x;                       // 0 .. NB*NC-1
    unsigned short* xd = xpad + (size_t)bc * XPSLICE;
#pragma unroll
    for (int e = threadIdx.x; e < 832; e += 256) {
        int row, col;
        if (e < 192)      { row = e >> 6;              col = e & 63; }
        else if (e < 384) { int f = e - 192; row = 59 + (f >> 6); col = f & 63; }
        else              { int f = e - 384; row = 3 + (f >> 3);
                            int c8 = f & 7;  col = (c8 < 3) ? c8 : 56 + c8; }
        xd[row * XPW + col] = 0;
    }
}

// ---------------------------------------------------------------------------
// K0b: w2 [16g*49][64] fp32 -> w2bf [g][64m][64k] bf16 (rows 49..63 zero).
// ---------------------------------------------------------------------------
__global__ __launch_bounds__(256) void prep_w2_kernel(
    const float* __restrict__ w2, __hip_bfloat16* __restrict__ w2bf) {
    int g = blockIdx.x;                        // 0..15
#pragma unroll 4
    for (int e = threadIdx.x; e < 64 * 64; e += 256) {
        int m = e >> 6, k = e & 63;
        float v = (m < KK) ? w2[((size_t)g * KK + m) * RED + k] : 0.0f;
        w2bf[(size_t)g * 4096 + e] = __float2bfloat16(v);
    }
}

// ---------------------------------------------------------------------------
// K1: t = relu(bn1(conv1x1(x, w1))) -> bf16, AND scatter x (as bf16) into
// xpad interior. Grid 784 1D (XCD-swizzled, 8x98) x 256 thr (4 waves).
// ---------------------------------------------------------------------------
__global__ __launch_bounds__(256) void conv1_kernel(
    const float* __restrict__ x, const float* __restrict__ w1,
    const float* __restrict__ g1, const float* __restrict__ be1,
    const float* __restrict__ mu1, const float* __restrict__ var1,
    __hip_bfloat16* __restrict__ t, unsigned short* __restrict__ xpad) {
    int lane = threadIdx.x & 63;
    int wv   = __builtin_amdgcn_readfirstlane(threadIdx.x >> 6);  // 0..3 SGPR
    // XCD swizzle: 784 = 8 * 98; logical = b*98 + half*49 + tile
    int wgid = blockIdx.x;
    int swz  = (wgid & 7) * 98 + (wgid >> 3);
    int b    = swz / 98;
    int rem  = swz % 98;
    int half = rem / 49;
    int tile = rem % 49;
    int rq = half * 4 + wv;                    // 0..7 -> outputs rq*8..rq*8+7
    int px = tile * 64 + lane;
    int h = px / HW, w = px % HW;

    const float* xb = x + (size_t)b * NC * NPX + px;
    unsigned short* xpw = xpad + (size_t)b * NC * XPSLICE
                        + (h + PADK) * XPW + (w + PADK);

    float acc[8];
#pragma unroll
    for (int j = 0; j < 8; ++j) acc[j] = 0.0f;

#pragma unroll 2
    for (int c0 = 0; c0 < NC; c0 += 16) {
        float xv[16];
#pragma unroll
        for (int i = 0; i < 16; ++i) xv[i] = xb[(size_t)(c0 + i) * NPX];
        if (half == 0 && wv == 0) {            // block+wave-uniform branch
#pragma unroll
            for (int i = 0; i < 16; ++i) {
                __hip_bfloat16 hv = __float2bfloat16(xv[i]);
                xpw[(size_t)(c0 + i) * XPSLICE] = *(unsigned short*)&hv;
            }
        }
#pragma unroll
        for (int j = 0; j < 8; ++j) {
            const float* wrow = w1 + (rq * 8 + j) * NC + c0;   // s_load
#pragma unroll
            for (int i = 0; i < 16; ++i)
                acc[j] = fmaf(xv[i], wrow[i], acc[j]);
        }
    }

    __hip_bfloat16* tb = t + (size_t)b * RED * NPX + px;
#pragma unroll
    for (int j = 0; j < 8; ++j) {
        int o = rq * 8 + j;
        float inv = g1[o] * rsqrtf(var1[o] + 1e-5f);
        float v = acc[j] * inv + (be1[o] - mu1[o] * inv);
        tb[(size_t)o * NPX] = __float2bfloat16(fmaxf(v, 0.0f));
    }
}

// ---------------------------------------------------------------------------
// K2: fused conv2(MFMA) -> involution -> bn2 -> relu.  ONE group per block.
// Grid 6272 1D (XCD-swizzled 8x784), 256 thr (4 waves). r9 skeleton, but ALL
// LDS in bf16: xtap [16ch][8rows] stride-72/580 (18.6 KB) + wls [49][68]
// (6.7 KB) = 25.2 KB -> LDS allows 6 blocks/CU; launch_bounds(256,5).
// Step 1 (T14): 4x b128 bf16 xtap loads (global->reg), written after A.
// Step 2 (phase A): MFMA wgt = w2g . t-tile (t gathered from global, L2-hot);
//         C+bias -> bf16 -> wls.
// Step 3: reg->LDS xtap b128 writes, one barrier.
// Step 4 (phase B): lane = (ch, px-quad). All LDS reads are aligned b64
//         (w0 % 4 == 0 -> 8B; strides 8B-multiples). Unpack bf16 via <<16.
// ---------------------------------------------------------------------------
__global__ __launch_bounds__(256, 5) void involution_kernel(
    const unsigned short* __restrict__ xpad, const __hip_bfloat16* __restrict__ t,
    const __hip_bfloat16* __restrict__ w2bf, const float* __restrict__ b2,
    const float* __restrict__ g2, const float* __restrict__ be2,
    const float* __restrict__ mu2, const float* __restrict__ var2,
    float* __restrict__ out) {
    __shared__ __align__(16) unsigned short xtap[GC * XT_CS];  // 18,560 B
    __shared__ __align__(16) unsigned short wls[KK * WSTR];    //  6,664 B

    int tid  = threadIdx.x;
    int lane = tid & 63;
    int wv   = __builtin_amdgcn_readfirstlane(tid >> 6);   // 0..3 SGPR
    // XCD swizzle: 6272 = 8 * 784; logical = b*784 + g*49 + tile
    int wgid = blockIdx.x;
    int swz  = (wgid & 7) * 784 + (wgid >> 3);
    int tile = swz % 49;
    int g    = (swz / 49) & 15;
    int b    = swz / 784;
    int px0 = tile * 64;
    int h0  = px0 / HW;                        // first pixel-row of tile

    const unsigned short* xpg = xpad + ((size_t)b * NC + (size_t)g * GC) * XPSLICE;

    // ---- step 1: issue xtap global loads (held in regs across phase A) ----
    // 16 ch x 8 rows x 64 cols bf16 = 16 KB = 1024 16B-chunks, 4 per thread.
    u16x8 xr[4];
#pragma unroll
    for (int u = 0; u < 4; ++u) {
        int cid = u * 256 + tid;               // 0..1023
        int ch  = cid >> 6;
        int rem = cid & 63;
        int rr  = rem >> 3, c8 = rem & 7;
        xr[u] = *(const u16x8*)(xpg + (size_t)ch * XPSLICE + (h0 + rr) * XPW + c8 * 8);
    }

    // ---- step 2: phase A MFMA  wgt[49x64px] = w2g[49x64r] . t[64r x 64px] ----
    {
        int l15 = lane & 15, l4 = lane >> 4;
        int pxc = px0 + wv * 16 + l15;
        const unsigned short* tg =
            (const unsigned short*)t + (size_t)b * RED * NPX + pxc;
        short8 bfr0, bfr1;
#pragma unroll
        for (int i = 0; i < 8; ++i) {
            bfr0[i] = (short)tg[(size_t)(l4 * 8 + i) * NPX];
            bfr1[i] = (short)tg[(size_t)(32 + l4 * 8 + i) * NPX];
        }

        const short* wA = (const short*)w2bf + (size_t)g * 4096;
        const float* bg = b2 + (size_t)g * KK;
        f32x4 acc0 = {0,0,0,0}, acc1 = {0,0,0,0}, acc2 = {0,0,0,0}, acc3 = {0,0,0,0};
#pragma unroll
        for (int mt = 0; mt < 4; ++mt) {
            const short* ap = wA + (mt * 16 + l15) * 64 + l4 * 8;
            short8 a0 = *(const short8*)(ap);
            short8 a1 = *(const short8*)(ap + 32);
            f32x4 a = (mt == 0) ? acc0 : (mt == 1) ? acc1 : (mt == 2) ? acc2 : acc3;
            a = __builtin_amdgcn_mfma_f32_16x16x32_bf16(a0, bfr0, a, 0, 0, 0);
            a = __builtin_amdgcn_mfma_f32_16x16x32_bf16(a1, bfr1, a, 0, 0, 0);
            if (mt == 0) acc0 = a; else if (mt == 1) acc1 = a;
            else if (mt == 2) acc2 = a; else acc3 = a;
        }
        // C write: wls[k][px] bf16, k = mt*16 + l4*4 + r, px = wv*16 + l15
        unsigned short* wl = wls + wv * 16 + l15;
#pragma unroll
        for (int mt = 0; mt < 4; ++mt) {
            f32x4 a = (mt == 0) ? acc0 : (mt == 1) ? acc1 : (mt == 2) ? acc2 : acc3;
#pragma unroll
            for (int r = 0; r < 4; ++r) {
                int k = mt * 16 + l4 * 4 + r;
                if (k < KK) {
                    __hip_bfloat16 hv = __float2bfloat16(a[r] + bg[k]);
                    wl[k * WSTR] = *(unsigned short*)&hv;
                }
            }
        }
    }

    // ---- step 3: write xtap regs to LDS (b128, 16B-aligned), one barrier ----
#pragma unroll
    for (int u = 0; u < 4; ++u) {
        int cid = u * 256 + tid;
        int ch  = cid >> 6;
        int rem = cid & 63;
        int rr  = rem >> 3, c8 = rem & 7;
        *(u16x8*)&xtap[ch * XT_CS + rr * XT_RS + c8 * 8] = xr[u];
    }
    __syncthreads();

    // ---- step 4: phase B, lane = (ch, 4-px quad), all-LDS bf16 taps ----
    int quad = tid & 15;                       // 0..15
    int ch   = tid >> 4;                       // 0..15
    int pxl  = quad * 4;                       // local px of quad start
    int px_a = px0 + pxl;
    int lh   = px_a / HW - h0;                 // 0 or 1 (quads don't straddle)
    int w0   = px_a % HW;                      // multiple of 4

    const unsigned short* xr0 = xtap + ch * XT_CS + lh * XT_RS + w0;
    float acc0 = 0.f, acc1 = 0.f, acc2 = 0.f, acc3 = 0.f;
#pragma unroll
    for (int i = 0; i < KS; ++i) {
        u16x4 t0 = *(const u16x4*)(xr0 + i * XT_RS);       // cols w0..w0+3
        u16x4 t1 = *(const u16x4*)(xr0 + i * XT_RS + 4);   // +4..+7
        u16x4 t2 = *(const u16x4*)(xr0 + i * XT_RS + 8);   // +8..+11
        float cc[12];
        cc[0] = bf2f(t0[0]); cc[1]  = bf2f(t0[1]); cc[2]  = bf2f(t0[2]); cc[3]  = bf2f(t0[3]);
        cc[4] = bf2f(t1[0]); cc[5]  = bf2f(t1[1]); cc[6]  = bf2f(t1[2]); cc[7]  = bf2f(t1[3]);
        cc[8] = bf2f(t2[0]); cc[9]  = bf2f(t2[1]); cc[10] = bf2f(t2[2]); cc[11] = bf2f(t2[3]);
#pragma unroll
        for (int j = 0; j < KS; ++j) {
            u16x4 wp = *(const u16x4*)&wls[(i * KS + j) * WSTR + pxl];
            acc0 = fmaf(bf2f(wp[0]), cc[j + 0], acc0);
            acc1 = fmaf(bf2f(wp[1]), cc[j + 1], acc1);
            acc2 = fmaf(bf2f(wp[2]), cc[j + 2], acc2);
            acc3 = fmaf(bf2f(wp[3]), cc[j + 3], acc3);
        }
    }

    int c_ = g * GC + ch;
    float inv = g2[c_] * rsqrtf(var2[c_] + 1e-5f);
    float off = be2[c_] - mu2[c_] * inv;
    f32x4 o;
    o[0] = fmaxf(acc0 * inv + off, 0.0f);
    o[1] = fmaxf(acc1 * inv + off, 0.0f);
    o[2] = fmaxf(acc2 * inv + off, 0.0f);
    o[3] = fmaxf(acc3 * inv + off, 0.0f);
    *(f32x4*)(out + ((size_t)b * NC + c_) * NPX + px_a) = o;
}

// ---------------------------------------------------------------------------
extern "C" void kernel_launch(void* const* d_in, const int* in_sizes, int n_in,
                              void* d_out, int out_size, void* d_ws, size_t ws_size,
                              hipStream_t stream) {
    const float* x    = (const float*)d_in[0];
    const float* w1   = (const float*)d_in[1];
    const float* g1   = (const float*)d_in[2];
    const float* be1  = (const float*)d_in[3];
    const float* mu1  = (const float*)d_in[4];
    const float* var1 = (const float*)d_in[5];
    const float* w2   = (const float*)d_in[6];
    const float* b2   = (const float*)d_in[7];
    const float* g2   = (const float*)d_in[8];
    const float* be2  = (const float*)d_in[9];
    const float* mu2  = (const float*)d_in[10];
    const float* var2 = (const float*)d_in[11];
    float* outp = (float*)d_out;

    // ws: xpad bf16 (16.3 MB) | t bf16 (3.2 MB) | w2bf bf16 (128 KB)
    unsigned short* xpad = (unsigned short*)d_ws;
    char* p = (char*)d_ws + (size_t)NB * NC * XPSLICE * sizeof(unsigned short);
    __hip_bfloat16* t = (__hip_bfloat16*)p;
    p += (size_t)NB * RED * NPX * sizeof(__hip_bfloat16);
    __hip_bfloat16* w2bf = (__hip_bfloat16*)p;

    prep_w2_kernel<<<NG, 256, 0, stream>>>(w2, w2bf);
    border_kernel<<<NB * NC, 256, 0, stream>>>(xpad);
    conv1_kernel<<<784, 256, 0, stream>>>(
        x, w1, g1, be1, mu1, var1, t, xpad);
    involution_kernel<<<6272, 256, 0, stream>>>(
        xpad, t, w2bf, b2, g2, be2, mu2, var2, outp);
}

// Round 12
// 64.697 us; speedup vs baseline: 1.5781x; 1.3650x over previous
//
#include <hip/hip_runtime.h>
#include <hip/hip_fp16.h>

// Problem constants
#define NB   8
#define NC   256
#define HW   56
#define NPX  3136          // 56*56
#define RED  64
#define NG   16
#define GC   16
#define KS   7
#define KK   49
#define PADK 3
#define XPH  62            // padded rows: 3 + 56 + 3
#define XPW  64            // padded row stride (elements)
#define XPSLICE (XPH * XPW)   // 3968 f16 per channel slice
#define XT_RS 72           // xtap row stride (f16): 144 B
#define XT_CS 584          // xtap ch stride (f16): 1168 B, 16B-multiple
#define WSTR  68           // wls px stride (f16)

typedef float f32x4 __attribute__((ext_vector_type(4)));
typedef _Float16 h16x4 __attribute__((ext_vector_type(4)));
typedef _Float16 h16x8 __attribute__((ext_vector_type(8)));

// ---------------------------------------------------------------------------
// K0: fused prep.  blocks 0..2047: pad+convert x -> xpad f16 (incl. border);
//     blocks 2048..2063: w2 -> w2h [g][64m][64k] f16 (rows 49..63 zero);
//     block  2064:       w1 -> w1h [64o][256c] f16.
// ---------------------------------------------------------------------------
__global__ __launch_bounds__(256) void prep_kernel(
    const float* __restrict__ x, const float* __restrict__ w1,
    const float* __restrict__ w2, _Float16* __restrict__ xpad,
    _Float16* __restrict__ w1h, _Float16* __restrict__ w2h) {
    int bid = blockIdx.x;
    if (bid < NB * NC) {
        const float* xs = x + (size_t)bid * NPX;
        _Float16* xd = xpad + (size_t)bid * XPSLICE;
#pragma unroll 4
        for (int e = threadIdx.x; e < XPSLICE; e += 256) {
            int row = e >> 6, col = e & 63;
            int h = row - PADK, w = col - PADK;
            float v = (h >= 0 && h < HW && w >= 0 && w < HW) ? xs[h * HW + w] : 0.0f;
            xd[e] = (_Float16)v;
        }
    } else if (bid < NB * NC + NG) {
        int g = bid - NB * NC;
#pragma unroll 4
        for (int e = threadIdx.x; e < 4096; e += 256) {
            int m = e >> 6, k = e & 63;
            float v = (m < KK) ? w2[((size_t)g * KK + m) * RED + k] : 0.0f;
            w2h[(size_t)g * 4096 + e] = (_Float16)v;
        }
    } else {
#pragma unroll 4
        for (int e = threadIdx.x; e < 64 * 256; e += 256)
            w1h[e] = (_Float16)w1[e];
    }
}

// ---------------------------------------------------------------------------
// K1: conv1 via MFMA f16.  tT[b][px][o] = relu(bn1(w1 . x))^T (f16).
// Grid 1568 (8b x 196 n-tiles; b = wgid&7 -> XCD-local batch), 64 thr = 1 wave.
// Wave computes C[64 o][16 px]: 8 k-steps x 4 m-tiles of mfma_16x16x32_f16.
// A = w1h rows (b128), B = xpad gathers (8 f16 per k-step, stride XPSLICE).
// Epilogue: bn1+relu, pack 4 f16, ONE b64 store per m-tile to tT.
// ---------------------------------------------------------------------------
__global__ __launch_bounds__(64) void conv1_kernel(
    const _Float16* __restrict__ xpad, const _Float16* __restrict__ w1h,
    const float* __restrict__ g1, const float* __restrict__ be1,
    const float* __restrict__ mu1, const float* __restrict__ var1,
    _Float16* __restrict__ tT) {
    int lane = threadIdx.x;
    int l15 = lane & 15, l4 = lane >> 4;
    int wgid = blockIdx.x;                 // 1568 = 8 * 196
    int b  = wgid & 7;                     // XCD-local batch
    int nt = wgid >> 3;                    // 0..195
    int px = nt * 16 + l15;
    int h = px / HW, w = px % HW;

    const _Float16* xp = xpad + (size_t)b * NC * XPSLICE
                       + (h + PADK) * XPW + (w + PADK);

    f32x4 acc0 = {0,0,0,0}, acc1 = {0,0,0,0}, acc2 = {0,0,0,0}, acc3 = {0,0,0,0};
#pragma unroll
    for (int kk = 0; kk < 8; ++kk) {
        h16x8 bfr;
#pragma unroll
        for (int i = 0; i < 8; ++i)
            bfr[i] = xp[(size_t)(kk * 32 + l4 * 8 + i) * XPSLICE];
#pragma unroll
        for (int mt = 0; mt < 4; ++mt) {
            const _Float16* ap = w1h + (mt * 16 + l15) * NC + kk * 32 + l4 * 8;
            h16x8 a = *(const h16x8*)ap;
            f32x4 c = (mt == 0) ? acc0 : (mt == 1) ? acc1 : (mt == 2) ? acc2 : acc3;
            c = __builtin_amdgcn_mfma_f32_16x16x32_f16(a, bfr, c, 0, 0, 0);
            if (mt == 0) acc0 = c; else if (mt == 1) acc1 = c;
            else if (mt == 2) acc2 = c; else acc3 = c;
        }
    }

    // epilogue: bn1 + relu -> f16, tT[b][px][o]
    _Float16* tb = tT + ((size_t)b * NPX + px) * RED;
#pragma unroll
    for (int mt = 0; mt < 4; ++mt) {
        f32x4 a = (mt == 0) ? acc0 : (mt == 1) ? acc1 : (mt == 2) ? acc2 : acc3;
        int o0 = mt * 16 + l4 * 4;
        h16x4 pk;
#pragma unroll
        for (int r = 0; r < 4; ++r) {
            int o = o0 + r;
            float inv = g1[o] * rsqrtf(var1[o] + 1e-5f);
            float v = a[r] * inv + (be1[o] - mu1[o] * inv);
            pk[r] = (_Float16)fmaxf(v, 0.0f);
        }
        *(h16x4*)(tb + o0) = pk;
    }
}

// ---------------------------------------------------------------------------
// K2: fused conv2(MFMA f16) -> involution -> bn2 -> relu.  ONE group/block.
// Grid 6272 (XCD-swizzled 8x784), 256 thr (4 waves). LDS all f16:
// xtap [16ch][8rows] (18.7 KB) + wls [49][68] (6.7 KB) = 25.4 KB.
// Step 1 (T14): 4x b128 f16 xtap loads (global->reg), written after phase A.
// Step 2: MFMA wgt = w2h . tT-tile; B-frags = TWO b128 loads from tT (was 16
//         scalar gathers). C+bias -> f16 -> wls.
// Step 3: reg->LDS xtap writes, one barrier.
// Step 4: phase B, lane = (ch, px-quad); f16 LDS reads + v_fma_mix
//         (float)h16 folds into the FMA -> no unpack instructions.
// ---------------------------------------------------------------------------
__global__ __launch_bounds__(256, 5) void involution_kernel(
    const _Float16* __restrict__ xpad, const _Float16* __restrict__ tT,
    const _Float16* __restrict__ w2h, const float* __restrict__ b2,
    const float* __restrict__ g2, const float* __restrict__ be2,
    const float* __restrict__ mu2, const float* __restrict__ var2,
    float* __restrict__ out) {
    __shared__ __align__(16) _Float16 xtap[GC * XT_CS];  // 18,688 B
    __shared__ __align__(16) _Float16 wls[KK * WSTR];    //  6,664 B

    int tid  = threadIdx.x;
    int lane = tid & 63;
    int wv   = __builtin_amdgcn_readfirstlane(tid >> 6);   // 0..3 SGPR
    // XCD swizzle: 6272 = 8 * 784; each XCD owns one batch
    int wgid = blockIdx.x;
    int swz  = (wgid & 7) * 784 + (wgid >> 3);
    int tile = swz % 49;
    int g    = (swz / 49) & 15;
    int b    = swz / 784;
    int px0 = tile * 64;
    int h0  = px0 / HW;

    const _Float16* xpg = xpad + ((size_t)b * NC + (size_t)g * GC) * XPSLICE;

    // ---- step 1: issue xtap global loads (held in regs across phase A) ----
    h16x8 xr[4];
#pragma unroll
    for (int u = 0; u < 4; ++u) {
        int cid = u * 256 + tid;               // 0..1023 16B-chunks
        int ch  = cid >> 6;
        int rem = cid & 63;
        int rr  = rem >> 3, c8 = rem & 7;
        xr[u] = *(const h16x8*)(xpg + (size_t)ch * XPSLICE + (h0 + rr) * XPW + c8 * 8);
    }

    // ---- step 2: phase A MFMA  wgt[49x64px] = w2h[49x64r] . tT[64px][64r] ----
    {
        int l15 = lane & 15, l4 = lane >> 4;
        int pxc = px0 + wv * 16 + l15;
        const _Float16* tp = tT + ((size_t)b * NPX + pxc) * RED + l4 * 8;
        h16x8 bfr0 = *(const h16x8*)tp;
        h16x8 bfr1 = *(const h16x8*)(tp + 32);

        const _Float16* wA = w2h + (size_t)g * 4096;
        const float* bg = b2 + (size_t)g * KK;
        f32x4 acc0 = {0,0,0,0}, acc1 = {0,0,0,0}, acc2 = {0,0,0,0}, acc3 = {0,0,0,0};
#pragma unroll
        for (int mt = 0; mt < 4; ++mt) {
            const _Float16* ap = wA + (mt * 16 + l15) * 64 + l4 * 8;
            h16x8 a0 = *(const h16x8*)(ap);
            h16x8 a1 = *(const h16x8*)(ap + 32);
            f32x4 a = (mt == 0) ? acc0 : (mt == 1) ? acc1 : (mt == 2) ? acc2 : acc3;
            a = __builtin_amdgcn_mfma_f32_16x16x32_f16(a0, bfr0, a, 0, 0, 0);
            a = __builtin_amdgcn_mfma_f32_16x16x32_f16(a1, bfr1, a, 0, 0, 0);
            if (mt == 0) acc0 = a; else if (mt == 1) acc1 = a;
            else if (mt == 2) acc2 = a; else acc3 = a;
        }
        // C write: wls[k][px] f16, k = mt*16 + l4*4 + r, px = wv*16 + l15
        _Float16* wl = wls + wv * 16 + l15;
#pragma unroll
        for (int mt = 0; mt < 4; ++mt) {
            f32x4 a = (mt == 0) ? acc0 : (mt == 1) ? acc1 : (mt == 2) ? acc2 : acc3;
#pragma unroll
            for (int r = 0; r < 4; ++r) {
                int k = mt * 16 + l4 * 4 + r;
                if (k < KK) wl[k * WSTR] = (_Float16)(a[r] + bg[k]);
            }
        }
    }

    // ---- step 3: write xtap regs to LDS (16B-aligned), one barrier ----
#pragma unroll
    for (int u = 0; u < 4; ++u) {
        int cid = u * 256 + tid;
        int ch  = cid >> 6;
        int rem = cid & 63;
        int rr  = rem >> 3, c8 = rem & 7;
        *(h16x8*)&xtap[ch * XT_CS + rr * XT_RS + c8 * 8] = xr[u];
    }
    __syncthreads();

    // ---- step 4: phase B, lane = (ch, 4-px quad), f16 LDS + fma_mix ----
    int quad = tid & 15;                       // 0..15
    int ch   = tid >> 4;                       // 0..15
    int pxl  = quad * 4;
    int px_a = px0 + pxl;
    int lh   = px_a / HW - h0;                 // 0 or 1
    int w0   = px_a % HW;                      // multiple of 4

    const _Float16* xr0 = xtap + ch * XT_CS + lh * XT_RS + w0;
    float acc0 = 0.f, acc1 = 0.f, acc2 = 0.f, acc3 = 0.f;
#pragma unroll
    for (int i = 0; i < KS; ++i) {
        h16x4 t0 = *(const h16x4*)(xr0 + i * XT_RS);
        h16x4 t1 = *(const h16x4*)(xr0 + i * XT_RS + 4);
        h16x4 t2 = *(const h16x4*)(xr0 + i * XT_RS + 8);
        float cc[12];
        cc[0] = (float)t0[0]; cc[1]  = (float)t0[1]; cc[2]  = (float)t0[2]; cc[3]  = (float)t0[3];
        cc[4] = (float)t1[0]; cc[5]  = (float)t1[1]; cc[6]  = (float)t1[2]; cc[7]  = (float)t1[3];
        cc[8] = (float)t2[0]; cc[9]  = (float)t2[1]; cc[10] = (float)t2[2]; cc[11] = (float)t2[3];
#pragma unroll
        for (int j = 0; j < KS; ++j) {
            h16x4 wp = *(const h16x4*)&wls[(i * KS + j) * WSTR + pxl];
            acc0 = fmaf((float)wp[0], cc[j + 0], acc0);
            acc1 = fmaf((float)wp[1], cc[j + 1], acc1);
            acc2 = fmaf((float)wp[2], cc[j + 2], acc2);
            acc3 = fmaf((float)wp[3], cc[j + 3], acc3);
        }
    }

    int c_ = g * GC + ch;
    float inv = g2[c_] * rsqrtf(var2[c_] + 1e-5f);
    float off = be2[c_] - mu2[c_] * inv;
    f32x4 o;
    o[0] = fmaxf(acc0 * inv + off, 0.0f);
    o[1] = fmaxf(acc1 * inv + off, 0.0f);
    o[2] = fmaxf(acc2 * inv + off, 0.0f);
    o[3] = fmaxf(acc3 * inv + off, 0.0f);
    *(f32x4*)(out + ((size_t)b * NC + c_) * NPX + px_a) = o;
}

// ---------------------------------------------------------------------------
extern "C" void kernel_launch(void* const* d_in, const int* in_sizes, int n_in,
                              void* d_out, int out_size, void* d_ws, size_t ws_size,
                              hipStream_t stream) {
    const float* x    = (const float*)d_in[0];
    const float* w1   = (const float*)d_in[1];
    const float* g1   = (const float*)d_in[2];
    const float* be1  = (const float*)d_in[3];
    const float* mu1  = (const float*)d_in[4];
    const float* var1 = (const float*)d_in[5];
    const float* w2   = (const float*)d_in[6];
    const float* b2   = (const float*)d_in[7];
    const float* g2   = (const float*)d_in[8];
    const float* be2  = (const float*)d_in[9];
    const float* mu2  = (const float*)d_in[10];
    const float* var2 = (const float*)d_in[11];
    float* outp = (float*)d_out;

    // ws: xpad f16 (16.3 MB) | tT f16 (3.2 MB) | w2h f16 (128 KB) | w1h (32 KB)
    _Float16* xpad = (_Float16*)d_ws;
    char* p = (char*)d_ws + (size_t)NB * NC * XPSLICE * sizeof(_Float16);
    _Float16* tT = (_Float16*)p;
    p += (size_t)NB * NPX * RED * sizeof(_Float16);
    _Float16* w2h = (_Float16*)p;
    p += (size_t)NG * 4096 * sizeof(_Float16);
    _Float16* w1h = (_Float16*)p;

    prep_kernel<<<NB * NC + NG + 1, 256, 0, stream>>>(x, w1, w2, xpad, w1h, w2h);
    conv1_kernel<<<1568, 64, 0, stream>>>(xpad, w1h, g1, be1, mu1, var1, tT);
    involution_kernel<<<6272, 256, 0, stream>>>(
        xpad, tT, w2h, b2, g2, be2, mu2, var2, outp);
}